// Round 3
// baseline (288.782 us; speedup 1.0000x reference)
//
#include <hip/hip_runtime.h>

#define TPB 256
#define NBLK_MAX 4096

__device__ __forceinline__ float relf(float x, float y) {
    float d = fabsf(x - y);
    float r = d * __builtin_amdgcn_rcpf(y);   // v_rcp_f32: ~1 ulp, no denorm-mode toggles
    return (y == 0.0f) ? d : r;               // branchless cndmask
}

__device__ __forceinline__ double term4(float4 xv, float4 yv) {
    return ((double)relf(xv.x, yv.x) + (double)relf(xv.y, yv.y))
         + ((double)relf(xv.z, yv.z) + (double)relf(xv.w, yv.w));
}

// 4 waves/EU -> ~128 VGPR budget: enough to hold 16 float4s in flight.
__global__ __launch_bounds__(TPB, 4) void rdl_partial_kernel(
    const float4* __restrict__ x, const float4* __restrict__ y,
    double* __restrict__ partial, int nvec) {
    double accd[4] = {0.0, 0.0, 0.0, 0.0};
    int tid = blockIdx.x * TPB + threadIdx.x;
    int stride = gridDim.x * TPB;

    int i = tid;
    // 8 float4-pairs per main iteration: 16 loads issued before any use.
    for (; i + 7 * stride < nvec; i += 8 * stride) {
        float4 xv[8], yv[8];
        #pragma unroll
        for (int u = 0; u < 8; ++u) xv[u] = x[i + u * stride];
        #pragma unroll
        for (int u = 0; u < 8; ++u) yv[u] = y[i + u * stride];
        #pragma unroll
        for (int u = 0; u < 8; ++u) accd[u & 3] += term4(xv[u], yv[u]);
    }
    for (; i < nvec; i += stride) accd[0] += term4(x[i], y[i]);

    double acc = (accd[0] + accd[1]) + (accd[2] + accd[3]);

    // wave (64-lane) reduction
    for (int off = 32; off > 0; off >>= 1)
        acc += __shfl_down(acc, off, 64);
    __shared__ double smem[TPB / 64];
    int lane = threadIdx.x & 63;
    int wid  = threadIdx.x >> 6;
    if (lane == 0) smem[wid] = acc;
    __syncthreads();
    if (threadIdx.x == 0) {
        double s = 0.0;
        #pragma unroll
        for (int w = 0; w < TPB / 64; ++w) s += smem[w];
        partial[blockIdx.x] = s;
    }
}

__global__ __launch_bounds__(TPB) void rdl_final_kernel(
    const double* __restrict__ partial, float* __restrict__ out,
    int nblocks, double invN) {
    double acc = 0.0;
    for (int i = threadIdx.x; i < nblocks; i += TPB)
        acc += partial[i];
    for (int off = 32; off > 0; off >>= 1)
        acc += __shfl_down(acc, off, 64);
    __shared__ double smem[TPB / 64];
    int lane = threadIdx.x & 63;
    int wid  = threadIdx.x >> 6;
    if (lane == 0) smem[wid] = acc;
    __syncthreads();
    if (threadIdx.x == 0) {
        double s = 0.0;
        #pragma unroll
        for (int w = 0; w < TPB / 64; ++w) s += smem[w];
        out[0] = (float)(s * invN);
    }
}

extern "C" void kernel_launch(void* const* d_in, const int* in_sizes, int n_in,
                              void* d_out, int out_size, void* d_ws, size_t ws_size,
                              hipStream_t stream) {
    const float* x = (const float*)d_in[0];
    const float* y = (const float*)d_in[1];
    int n = in_sizes[0];          // 33554432, divisible by 4
    int nvec = n / 4;

    // Adapt partial count to workspace size (grid-stride keeps any nblk correct).
    int nblk = (int)(ws_size / sizeof(double));
    if (nblk > NBLK_MAX) nblk = NBLK_MAX;
    if (nblk < 1) nblk = 1;

    double* partial = (double*)d_ws;

    rdl_partial_kernel<<<nblk, TPB, 0, stream>>>(
        (const float4*)x, (const float4*)y, partial, nvec);
    rdl_final_kernel<<<1, TPB, 0, stream>>>(
        partial, (float*)d_out, nblk, 1.0 / (double)n);
}

// Round 4
// 284.868 us; speedup vs baseline: 1.0137x; 1.0137x over previous
//
#include <hip/hip_runtime.h>

#define TPB 256
#define NBLK_MAX 8192

__device__ __forceinline__ float relf(float x, float y) {
    float d = fabsf(x - y);
    float r = d * __builtin_amdgcn_rcpf(y);   // v_rcp_f32: ~1 ulp, no denorm toggles
    return (y == 0.0f) ? d : r;               // branchless cndmask
}

// Slim-register streaming kernel: TLP over ILP. VGPR target ~20 so 32 waves/CU fit.
__global__ __launch_bounds__(TPB) void rdl_partial_kernel(
    const float4* __restrict__ x, const float4* __restrict__ y,
    double* __restrict__ partial, int nvec) {
    float accf0 = 0.0f, accf1 = 0.0f;   // two rotating f32 chains: short post-load shadow
    int tid = blockIdx.x * TPB + threadIdx.x;
    int stride = gridDim.x * TPB;

    #pragma unroll 4
    for (int i = tid; i < nvec; i += stride) {
        float4 xv = x[i];
        float4 yv = y[i];
        accf0 += relf(xv.x, yv.x) + relf(xv.z, yv.z);
        accf1 += relf(xv.y, yv.y) + relf(xv.w, yv.w);
    }

    double acc = (double)accf0 + (double)accf1;

    // wave (64-lane) reduction in f64
    for (int off = 32; off > 0; off >>= 1)
        acc += __shfl_down(acc, off, 64);
    __shared__ double smem[TPB / 64];
    int lane = threadIdx.x & 63;
    int wid  = threadIdx.x >> 6;
    if (lane == 0) smem[wid] = acc;
    __syncthreads();
    if (threadIdx.x == 0) {
        double s = 0.0;
        #pragma unroll
        for (int w = 0; w < TPB / 64; ++w) s += smem[w];
        partial[blockIdx.x] = s;
    }
}

__global__ __launch_bounds__(TPB) void rdl_final_kernel(
    const double* __restrict__ partial, float* __restrict__ out,
    int nblocks, double invN) {
    double acc = 0.0;
    for (int i = threadIdx.x; i < nblocks; i += TPB)
        acc += partial[i];
    for (int off = 32; off > 0; off >>= 1)
        acc += __shfl_down(acc, off, 64);
    __shared__ double smem[TPB / 64];
    int lane = threadIdx.x & 63;
    int wid  = threadIdx.x >> 6;
    if (lane == 0) smem[wid] = acc;
    __syncthreads();
    if (threadIdx.x == 0) {
        double s = 0.0;
        #pragma unroll
        for (int w = 0; w < TPB / 64; ++w) s += smem[w];
        out[0] = (float)(s * invN);
    }
}

extern "C" void kernel_launch(void* const* d_in, const int* in_sizes, int n_in,
                              void* d_out, int out_size, void* d_ws, size_t ws_size,
                              hipStream_t stream) {
    const float* x = (const float*)d_in[0];
    const float* y = (const float*)d_in[1];
    int n = in_sizes[0];          // 33554432, divisible by 4
    int nvec = n / 4;

    int nblk = (int)(ws_size / sizeof(double));
    if (nblk > NBLK_MAX) nblk = NBLK_MAX;
    if (nblk < 1) nblk = 1;

    double* partial = (double*)d_ws;

    rdl_partial_kernel<<<nblk, TPB, 0, stream>>>(
        (const float4*)x, (const float4*)y, partial, nvec);
    rdl_final_kernel<<<1, TPB, 0, stream>>>(
        partial, (float*)d_out, nblk, 1.0 / (double)n);
}

// Round 5
// 274.610 us; speedup vs baseline: 1.0516x; 1.0374x over previous
//
#include <hip/hip_runtime.h>

#define TPB 256
#define U 4
#define CHUNK (TPB * U)     // float4s per array per block-iteration (1024 = 16 KB/array)
#define NBLK 1024           // 4 blocks/CU; partials fit in 8 KB of d_ws

typedef __attribute__((address_space(1))) const void* gas_ptr;
typedef __attribute__((address_space(3))) void* las_ptr;

__device__ __forceinline__ float relf(float x, float y) {
    float d = fabsf(x - y);
    float r = d * __builtin_amdgcn_rcpf(y);   // ~1 ulp, no denorm-mode toggles
    return (y == 0.0f) ? d : r;               // branchless cndmask
}

__global__ __launch_bounds__(TPB) void rdl_partial_kernel(
    const float4* __restrict__ x, const float4* __restrict__ y,
    double* __restrict__ partial, int nvec) {

    __shared__ float4 lx[U][TPB];   // 16 KB
    __shared__ float4 ly[U][TPB];   // 16 KB

    const int t = threadIdx.x;
    const int w = t >> 6;           // wave id in block
    double accd = 0.0;

    const int nchunk = nvec / CHUNK;
    for (int c = blockIdx.x; c < nchunk; c += gridDim.x) {
        const int base = c * CHUNK;
        __syncthreads();            // prior ds_reads drained; LDS safe to overwrite
        // 8 zero-VGPR DMA loads in flight per wave (8 KB/wave outstanding)
        #pragma unroll
        for (int u = 0; u < U; ++u)
            __builtin_amdgcn_global_load_lds(
                (gas_ptr)(x + base + u * TPB + t),
                (las_ptr)&lx[u][w * 64], 16, 0, 0);
        #pragma unroll
        for (int u = 0; u < U; ++u)
            __builtin_amdgcn_global_load_lds(
                (gas_ptr)(y + base + u * TPB + t),
                (las_ptr)&ly[u][w * 64], 16, 0, 0);
        __syncthreads();            // forces s_waitcnt vmcnt(0): DMA complete

        float a0 = 0.f, a1 = 0.f;   // short f32 chains (32 terms), promoted below
        #pragma unroll
        for (int u = 0; u < U; ++u) {
            float4 xv = lx[u][t];
            float4 yv = ly[u][t];
            a0 += relf(xv.x, yv.x) + relf(xv.z, yv.z);
            a1 += relf(xv.y, yv.y) + relf(xv.w, yv.w);
        }
        accd += (double)(a0 + a1);
    }

    // tail (empty: CHUNK divides nvec for N=2^25), kept for generality
    for (int i = nchunk * CHUNK + blockIdx.x * TPB + t; i < nvec;
         i += gridDim.x * TPB) {
        float4 xv = x[i], yv = y[i];
        accd += (double)(relf(xv.x, yv.x) + relf(xv.z, yv.z)
                       + relf(xv.y, yv.y) + relf(xv.w, yv.w));
    }

    // wave (64-lane) reduction in f64
    double acc = accd;
    for (int off = 32; off > 0; off >>= 1)
        acc += __shfl_down(acc, off, 64);
    __shared__ double smem[TPB / 64];
    int lane = t & 63;
    if (lane == 0) smem[w] = acc;
    __syncthreads();
    if (t == 0) {
        double s = 0.0;
        #pragma unroll
        for (int wi = 0; wi < TPB / 64; ++wi) s += smem[wi];
        partial[blockIdx.x] = s;
    }
}

__global__ __launch_bounds__(TPB) void rdl_final_kernel(
    const double* __restrict__ partial, float* __restrict__ out,
    int nblocks, double invN) {
    double acc = 0.0;
    for (int i = threadIdx.x; i < nblocks; i += TPB)
        acc += partial[i];
    for (int off = 32; off > 0; off >>= 1)
        acc += __shfl_down(acc, off, 64);
    __shared__ double smem[TPB / 64];
    int lane = threadIdx.x & 63;
    int wid  = threadIdx.x >> 6;
    if (lane == 0) smem[wid] = acc;
    __syncthreads();
    if (threadIdx.x == 0) {
        double s = 0.0;
        #pragma unroll
        for (int w = 0; w < TPB / 64; ++w) s += smem[w];
        out[0] = (float)(s * invN);
    }
}

extern "C" void kernel_launch(void* const* d_in, const int* in_sizes, int n_in,
                              void* d_out, int out_size, void* d_ws, size_t ws_size,
                              hipStream_t stream) {
    const float* x = (const float*)d_in[0];
    const float* y = (const float*)d_in[1];
    int n = in_sizes[0];          // 33554432, divisible by 4
    int nvec = n / 4;

    double* partial = (double*)d_ws;   // NBLK * 8 = 8 KB scratch

    rdl_partial_kernel<<<NBLK, TPB, 0, stream>>>(
        (const float4*)x, (const float4*)y, partial, nvec);
    rdl_final_kernel<<<1, TPB, 0, stream>>>(
        partial, (float*)d_out, NBLK, 1.0 / (double)n);
}